// Round 8
// baseline (1094.256 us; speedup 1.0000x reference)
//
#include <hip/hip_runtime.h>
#include <hip/hip_bf16.h>

typedef __bf16 bf16x8 __attribute__((ext_vector_type(8)));
typedef float f32x4 __attribute__((ext_vector_type(4)));

#define T_TOK 4096
#define H_DIM 1024
#define F_DIM 2048
#define NEXP 8
#define TOTROWS 8192   // T_TOK * TOP_K, always exact (top-2 distinct experts)
#define MAXTILES 80    // 128-row tiles

__device__ inline unsigned short f2b(float f) {
    unsigned int u = __float_as_uint(f);
    unsigned int r = (u + 0x7fffu + ((u >> 16) & 1u)) >> 16;
    return (unsigned short)r;
}

// ---------------- router: logits -> softmax -> top2 -> renorm (4 tokens/block, no atomics) ----
__global__ __launch_bounds__(256) void router_kernel(const float* __restrict__ x,
                                                     const float* __restrict__ gw,
                                                     int* __restrict__ sel, float* __restrict__ selw) {
    int t = blockIdx.x * 4 + (threadIdx.x >> 6);
    int lane = threadIdx.x & 63;
    float acc[8] = {0.f,0.f,0.f,0.f,0.f,0.f,0.f,0.f};
    const float* xr = x + (size_t)t * H_DIM;
    for (int h = lane; h < H_DIM; h += 64) {
        float xv = xr[h];
        const float4* g = (const float4*)(gw + h * 8);
        float4 g0 = g[0], g1 = g[1];
        acc[0] += xv * g0.x; acc[1] += xv * g0.y; acc[2] += xv * g0.z; acc[3] += xv * g0.w;
        acc[4] += xv * g1.x; acc[5] += xv * g1.y; acc[6] += xv * g1.z; acc[7] += xv * g1.w;
    }
#pragma unroll
    for (int off = 32; off >= 1; off >>= 1)
#pragma unroll
        for (int e = 0; e < 8; ++e)
            acc[e] += __shfl_down(acc[e], off);
    if (lane == 0) {
        float mx = acc[0];
#pragma unroll
        for (int e = 1; e < 8; ++e) mx = fmaxf(mx, acc[e]);
        float p[8]; float s = 0.f;
#pragma unroll
        for (int e = 0; e < 8; ++e) { p[e] = expf(acc[e] - mx); s += p[e]; }
        float inv_s = 1.f / s;
#pragma unroll
        for (int e = 0; e < 8; ++e) p[e] *= inv_s;
        int e1 = 0; float p1 = p[0];
#pragma unroll
        for (int e = 1; e < 8; ++e) if (p[e] > p1) { p1 = p[e]; e1 = e; }
        int e2 = -1; float p2 = -1.f;
#pragma unroll
        for (int e = 0; e < 8; ++e) { if (e == e1) continue; if (p[e] > p2) { p2 = p[e]; e2 = e; } }
        float inv = 1.f / (p1 + p2);
        sel[t * 2 + 0] = e1; sel[t * 2 + 1] = e2;
        selw[t * 2 + 0] = p1 * inv; selw[t * 2 + 1] = p2 * inv;
    }
}

// ---------------- scan: histogram sel -> cnt/off/fill/tile table (1 block) ----------------
__global__ __launch_bounds__(256) void scan_kernel(const int* __restrict__ sel,
                                                   int* __restrict__ cnt, int* __restrict__ off,
                                                   int* __restrict__ fill,
                                                   int* __restrict__ tileExp, int* __restrict__ tileM0) {
    __shared__ int h[NEXP];
    int tid = threadIdx.x;
    if (tid < NEXP) h[tid] = 0;
    __syncthreads();
    for (int i = tid; i < TOTROWS; i += 256) atomicAdd(&h[sel[i]], 1);
    __syncthreads();
    if (tid == 0) {
        int o = 0;
        for (int e = 0; e < NEXP; ++e) { cnt[e] = h[e]; off[e] = o; o += h[e]; fill[e] = 0; }
        int nt = 0;
        for (int e = 0; e < NEXP; ++e)
            for (int m0 = 0; m0 < h[e]; m0 += 128) { tileExp[nt] = e; tileM0[nt] = m0; nt++; }
        for (int i = nt; i < MAXTILES; ++i) { tileExp[i] = -1; tileM0[i] = 0; }
    }
}

// ---------------- assign: ballot-rank slots, 1 atomic/expert/block (256 atomics total) -------
__global__ __launch_bounds__(256) void assign_kernel(const int* __restrict__ sel,
                                                     const float* __restrict__ selw,
                                                     const int* __restrict__ off,
                                                     int* __restrict__ fill,
                                                     float* __restrict__ rowWgt,
                                                     int* __restrict__ tokRow) {
    __shared__ int wcnt[4][NEXP];
    __shared__ int bbase[NEXP];
    int tid = threadIdx.x, lane = tid & 63, w = tid >> 6;
    int i = blockIdx.x * 256 + tid;          // 32 blocks x 256 = 8192 entries
    int e = sel[i];
    unsigned long long below = (1ULL << lane) - 1;
    int myrank = 0;
#pragma unroll
    for (int x = 0; x < NEXP; ++x) {
        unsigned long long m = __ballot(e == x);
        if (lane == 0) wcnt[w][x] = __popcll(m);
        if (e == x) myrank = __popcll(m & below);
    }
    __syncthreads();
    if (tid < NEXP) {
        int tot = wcnt[0][tid] + wcnt[1][tid] + wcnt[2][tid] + wcnt[3][tid];
        bbase[tid] = atomicAdd(&fill[tid], tot);
    }
    __syncthreads();
    int wb = 0;
    for (int w2 = 0; w2 < w; ++w2) wb += wcnt[w2][e];
    int r = off[e] + bbase[e] + wb + myrank;
    tokRow[i] = r;
    rowWgt[r] = selw[i];
}

// ---------------- copy: x row (bf16) to both expert rows (no atomics) ----------------
__global__ __launch_bounds__(256) void copy_kernel(const int* __restrict__ tokRow,
                                                   const float* __restrict__ x,
                                                   unsigned short* __restrict__ Xg) {
    int t = blockIdx.x;
    int tid = threadIdx.x;
    int r1 = tokRow[t * 2 + 0], r2 = tokRow[t * 2 + 1];
    float4 v = ((const float4*)(x + (size_t)t * H_DIM))[tid];
    ushort4 o;
    o.x = f2b(v.x); o.y = f2b(v.y); o.z = f2b(v.z); o.w = f2b(v.w);
    ((ushort4*)(Xg + (size_t)r1 * H_DIM))[tid] = o;
    ((ushort4*)(Xg + (size_t)r2 * H_DIM))[tid] = o;
}

// ---------------- fused transpose+cvt for all 3 weight tensors ----------------
__global__ __launch_bounds__(256) void transpose_cvt_kernel(
        const float* __restrict__ w_up, const float* __restrict__ w_gate,
        const float* __restrict__ w_down,
        unsigned short* __restrict__ wTu, unsigned short* __restrict__ wTg,
        unsigned short* __restrict__ wTd) {
    __shared__ unsigned short lt[64 * 68];
    int z = blockIdx.z;
    int e = blockIdx.y;
    const float* src; unsigned short* dst; int R, C, tr, tc;
    if (z == 0)      { src = w_up;   dst = wTu; R = H_DIM; C = F_DIM; }
    else if (z == 1) { src = w_gate; dst = wTg; R = H_DIM; C = F_DIM; }
    else             { src = w_down; dst = wTd; R = F_DIM; C = H_DIM; }
    if (R == H_DIM) { tc = blockIdx.x & 31; tr = blockIdx.x >> 5; }
    else            { tc = blockIdx.x & 15; tr = blockIdx.x >> 4; }
    const float* s = src + (size_t)e * H_DIM * F_DIM;
    unsigned short* d = dst + (size_t)e * H_DIM * F_DIM;
    int r0 = tr * 64, c0 = tc * 64;
    int tid = threadIdx.x;
    int fc = tid & 15, row = tid >> 4;
#pragma unroll
    for (int i = 0; i < 4; ++i) {
        int r = row + i * 16;
        float4 v = *(const float4*)(s + (size_t)(r0 + r) * C + c0 + fc * 4);
        lt[(fc * 4 + 0) * 68 + r] = f2b(v.x);
        lt[(fc * 4 + 1) * 68 + r] = f2b(v.y);
        lt[(fc * 4 + 2) * 68 + r] = f2b(v.z);
        lt[(fc * 4 + 3) * 68 + r] = f2b(v.w);
    }
    __syncthreads();
    int ch = tid & 7, cc = tid >> 3;
#pragma unroll
    for (int i = 0; i < 2; ++i) {
        int c = cc + i * 32;
        uint2 lo = *(const uint2*)&lt[c * 68 + ch * 8];
        uint2 hi = *(const uint2*)&lt[c * 68 + ch * 8 + 4];
        uint4 o = make_uint4(lo.x, lo.y, hi.x, hi.y);
        *(uint4*)(d + (size_t)(c0 + c) * R + r0 + ch * 8) = o;
    }
}

// =============== up/gate GEMM: 128x128, BK=32, REG-staged (R5-proven), 3 blocks/CU ===========
// Per K-tile (one barrier): {12 ds_read frags | 6 ds_write (tile t+1, regs loaded 2 tiles
// ago -> compiler emits counted vmcnt) | 6 global_load (tile t+2 -> regs) | 32 MFMA |
// lgkm(0); s_barrier}.  Occupancy bump vs R5: launch_bounds (256,3), 48KB x3 = 144KB LDS.
__global__ __launch_bounds__(256, 3) void gemm_upgate_kernel(
        const unsigned short* __restrict__ Xg,
        const unsigned short* __restrict__ wTu,   // [E][F][H] (k-major)
        const unsigned short* __restrict__ wTg,
        unsigned short* __restrict__ inner,       // [TOTROWS][F]
        const int* __restrict__ tileExp, const int* __restrict__ tileM0,
        const int* __restrict__ off, const int* __restrict__ cnt) {
    __shared__ __align__(16) unsigned short la[2][4096];    // 8KB x2 (128x32)
    __shared__ __align__(16) unsigned short lbu[2][4096];
    __shared__ __align__(16) unsigned short lbg[2][4096];   // 48KB total -> 3 blocks/CU
    int bt = blockIdx.y;
    int e = tileExp[bt];
    if (e < 0) return;
    int m0 = tileM0[bt];
    int r0 = off[e] + m0;
    int valid = cnt[e] - m0;
    int f0 = blockIdx.x * 128;
    const unsigned short* aB  = Xg + (size_t)r0 * H_DIM;
    const unsigned short* buW = wTu + (size_t)e * F_DIM * H_DIM + (size_t)f0 * H_DIM;
    const unsigned short* bgW = wTg + (size_t)e * F_DIM * H_DIM + (size_t)f0 * H_DIM;
    int tid = threadIdx.x;
    int lane = tid & 63, wid = tid >> 6;   // 4 waves
    int wm = wid >> 1, wn = wid & 1;       // 2M x 2N -> 64x64 per wave (dual U+G acc)
    int l16 = lane & 15, quad = lane >> 4;

    // staging map: 512 chunks/tile; thread owns chunks tid and tid+256 (all 3 arrays share it)
    int rA0 = tid >> 2, rA1 = rA0 + 64;
    int s0 = rA0 * H_DIM + (tid & 3) * 8;
    int s1 = rA1 * H_DIM + (tid & 3) * 8;
    int d0 = rA0 * 32 + (((tid & 3) ^ (rA0 & 3)) << 3);
    int d1 = rA1 * 32 + (((tid & 3) ^ (rA1 & 3)) << 3);

    // fragment LDS indices (ushort units)
    int aIdx[4], bIdx[4];
#pragma unroll
    for (int i = 0; i < 4; ++i) {
        int lr = wm * 64 + i * 16 + l16;
        aIdx[i] = lr * 32 + ((quad ^ (lr & 3)) << 3);
    }
#pragma unroll
    for (int j = 0; j < 4; ++j) {
        int lr = wn * 64 + j * 16 + l16;
        bIdx[j] = lr * 32 + ((quad ^ (lr & 3)) << 3);
    }

    f32x4 accU[4][4], accG[4][4];
#pragma unroll
    for (int i = 0; i < 4; ++i)
#pragma unroll
        for (int j = 0; j < 4; ++j) { accU[i][j] = (f32x4)0.f; accG[i][j] = (f32x4)0.f; }

    uint4 va0, va1, vu0, vu1, vg0, vg1;   // staging regs (one tile)

#define UPG_LOAD(K0) do {                                        \
    va0 = *(const uint4*)(aB + s0 + (K0));                       \
    va1 = *(const uint4*)(aB + s1 + (K0));                       \
    vu0 = *(const uint4*)(buW + s0 + (K0));                      \
    vu1 = *(const uint4*)(buW + s1 + (K0));                      \
    vg0 = *(const uint4*)(bgW + s0 + (K0));                      \
    vg1 = *(const uint4*)(bgW + s1 + (K0));                      \
} while (0)
#define UPG_WRITE(NB) do {                                       \
    *(uint4*)&la[NB][d0]  = va0;  *(uint4*)&la[NB][d1]  = va1;   \
    *(uint4*)&lbu[NB][d0] = vu0;  *(uint4*)&lbu[NB][d1] = vu1;   \
    *(uint4*)&lbg[NB][d0] = vg0;  *(uint4*)&lbg[NB][d1] = vg1;   \
} while (0)

    // prologue: tile0 -> LDS buf0; tile1 -> regs
    UPG_LOAD(0);
    UPG_WRITE(0);
    UPG_LOAD(32);
    asm volatile("s_waitcnt lgkmcnt(0)" ::: "memory");
    __builtin_amdgcn_s_barrier();
    __builtin_amdgcn_sched_barrier(0);

    for (int t = 0; t < 32; ++t) {        // K = 1024/32 = 32 tiles
        int cur = t & 1, nxt = cur ^ 1;
        const unsigned short* lac = la[cur];
        const unsigned short* luc = lbu[cur];
        const unsigned short* lgc = lbg[cur];
        bf16x8 af[4], bu[4], bg[4];
#pragma unroll
        for (int i = 0; i < 4; ++i) af[i] = *(const bf16x8*)(lac + aIdx[i]);
#pragma unroll
        for (int j = 0; j < 4; ++j) {
            bu[j] = *(const bf16x8*)(luc + bIdx[j]);
            bg[j] = *(const bf16x8*)(lgc + bIdx[j]);
        }
        if (t < 31) UPG_WRITE(nxt);          // publish tile t+1 (regs -> LDS)
        if (t < 30) UPG_LOAD((t + 2) * 32);  // prefetch tile t+2 (global -> regs)
        __builtin_amdgcn_s_setprio(1);
#pragma unroll
        for (int i = 0; i < 4; ++i)
#pragma unroll
            for (int j = 0; j < 4; ++j) {
                accU[i][j] = __builtin_amdgcn_mfma_f32_16x16x32_bf16(af[i], bu[j], accU[i][j], 0, 0, 0);
                accG[i][j] = __builtin_amdgcn_mfma_f32_16x16x32_bf16(af[i], bg[j], accG[i][j], 0, 0, 0);
            }
        __builtin_amdgcn_s_setprio(0);
        asm volatile("s_waitcnt lgkmcnt(0)" ::: "memory");   // ds_writes drained
        __builtin_amdgcn_s_barrier();
        __builtin_amdgcn_sched_barrier(0);
    }
#undef UPG_LOAD
#undef UPG_WRITE

#pragma unroll
    for (int i = 0; i < 4; ++i) {
#pragma unroll
        for (int rr = 0; rr < 4; ++rr) {
            int ml = wm * 64 + i * 16 + quad * 4 + rr;
            if (ml >= valid) continue;
            size_t base = (size_t)(r0 + ml) * F_DIM + f0;
#pragma unroll
            for (int j = 0; j < 4; ++j) {
                float u = accU[i][j][rr];
                float g = accG[i][j][rr];
                float v = u * __builtin_amdgcn_rcpf(1.f + __expf(-u)) * g;   // silu(up)*gate
                inner[base + wn * 64 + j * 16 + l16] = f2b(v);
            }
        }
    }
}

// =============== down GEMM: 128x128, BK=32, REG-staged, 256 thr / 4 waves, 3 blocks/CU =======
__global__ __launch_bounds__(256, 3) void gemm_down_kernel(
        const unsigned short* __restrict__ inner,  // [TOTROWS][F]
        const unsigned short* __restrict__ wTd,    // [E][H][F] (k-major)
        float* __restrict__ part,                  // [TOTROWS][H]
        const int* __restrict__ tileExp, const int* __restrict__ tileM0,
        const int* __restrict__ off, const int* __restrict__ cnt,
        const float* __restrict__ rowWgt) {
    __shared__ __align__(16) unsigned short la[2][4096];   // 8KB x2 (128x32)
    __shared__ __align__(16) unsigned short lb[2][4096];   // 32KB total -> 3 blocks/CU
    int bt = blockIdx.y;
    int e = tileExp[bt];
    if (e < 0) return;
    int m0 = tileM0[bt];
    int r0 = off[e] + m0;
    int valid = cnt[e] - m0;
    int h0 = blockIdx.x * 128;
    const unsigned short* aB = inner + (size_t)r0 * F_DIM;
    const unsigned short* bp = wTd + (size_t)e * H_DIM * F_DIM + (size_t)h0 * F_DIM;
    int tid = threadIdx.x;
    int lane = tid & 63, wid = tid >> 6;   // 4 waves
    int wm = wid >> 1, wn = wid & 1;       // 2M x 2N -> 64x64 per wave
    int l16 = lane & 15, quad = lane >> 4;

    int rA0 = tid >> 2, rA1 = rA0 + 64;
    int s0 = rA0 * F_DIM + (tid & 3) * 8;
    int s1 = rA1 * F_DIM + (tid & 3) * 8;
    int d0 = rA0 * 32 + (((tid & 3) ^ (rA0 & 3)) << 3);
    int d1 = rA1 * 32 + (((tid & 3) ^ (rA1 & 3)) << 3);

    int aIdx[4], bIdx[4];
#pragma unroll
    for (int i = 0; i < 4; ++i) {
        int lr = wm * 64 + i * 16 + l16;
        aIdx[i] = lr * 32 + ((quad ^ (lr & 3)) << 3);
    }
#pragma unroll
    for (int j = 0; j < 4; ++j) {
        int lr = wn * 64 + j * 16 + l16;
        bIdx[j] = lr * 32 + ((quad ^ (lr & 3)) << 3);
    }

    f32x4 acc[4][4];
#pragma unroll
    for (int i = 0; i < 4; ++i)
#pragma unroll
        for (int j = 0; j < 4; ++j) acc[i][j] = (f32x4)0.f;

    uint4 va0, va1, vb0, vb1;

#define DWN_LOAD(K0) do {                                        \
    va0 = *(const uint4*)(aB + s0 + (K0));                       \
    va1 = *(const uint4*)(aB + s1 + (K0));                       \
    vb0 = *(const uint4*)(bp + s0 + (K0));                       \
    vb1 = *(const uint4*)(bp + s1 + (K0));                       \
} while (0)
#define DWN_WRITE(NB) do {                                       \
    *(uint4*)&la[NB][d0] = va0;  *(uint4*)&la[NB][d1] = va1;     \
    *(uint4*)&lb[NB][d0] = vb0;  *(uint4*)&lb[NB][d1] = vb1;     \
} while (0)

    DWN_LOAD(0);
    DWN_WRITE(0);
    DWN_LOAD(32);
    asm volatile("s_waitcnt lgkmcnt(0)" ::: "memory");
    __builtin_amdgcn_s_barrier();
    __builtin_amdgcn_sched_barrier(0);

    for (int t = 0; t < 64; ++t) {        // K = 2048/32 = 64 tiles
        int cur = t & 1, nxt = cur ^ 1;
        const unsigned short* lac = la[cur];
        const unsigned short* lbc = lb[cur];
        bf16x8 af[4], bw[4];
#pragma unroll
        for (int i = 0; i < 4; ++i) af[i] = *(const bf16x8*)(lac + aIdx[i]);
#pragma unroll
        for (int j = 0; j < 4; ++j) bw[j] = *(const bf16x8*)(lbc + bIdx[j]);
        if (t < 63) DWN_WRITE(nxt);
        if (t < 62) DWN_LOAD((t + 2) * 32);
        __builtin_amdgcn_s_setprio(1);
#pragma unroll
        for (int i = 0; i < 4; ++i)
#pragma unroll
            for (int j = 0; j < 4; ++j)
                acc[i][j] = __builtin_amdgcn_mfma_f32_16x16x32_bf16(af[i], bw[j], acc[i][j], 0, 0, 0);
        __builtin_amdgcn_s_setprio(0);
        asm volatile("s_waitcnt lgkmcnt(0)" ::: "memory");
        __builtin_amdgcn_s_barrier();
        __builtin_amdgcn_sched_barrier(0);
    }
#undef DWN_LOAD
#undef DWN_WRITE

#pragma unroll
    for (int i = 0; i < 4; ++i) {
#pragma unroll
        for (int rr = 0; rr < 4; ++rr) {
            int ml = wm * 64 + i * 16 + quad * 4 + rr;
            if (ml >= valid) continue;
            int gr = r0 + ml;
            float w = rowWgt[gr];
            float* orow = part + (size_t)gr * H_DIM + h0;
#pragma unroll
            for (int j = 0; j < 4; ++j)
                orow[wn * 64 + j * 16 + l16] = w * acc[i][j][rr];
        }
    }
}

// ---------------- combine: out[t] = part[r1] + part[r2] ----------------
__global__ __launch_bounds__(256) void combine_kernel(const float* __restrict__ part,
                                                      const int* __restrict__ tokRow,
                                                      float* __restrict__ out) {
    int t = blockIdx.x;
    int r1 = tokRow[t * 2 + 0], r2 = tokRow[t * 2 + 1];
    int i = threadIdx.x;
    float4 a = ((const float4*)(part + (size_t)r1 * H_DIM))[i];
    float4 b = ((const float4*)(part + (size_t)r2 * H_DIM))[i];
    float4 o;
    o.x = a.x + b.x; o.y = a.y + b.y; o.z = a.z + b.z; o.w = a.w + b.w;
    ((float4*)(out + (size_t)t * H_DIM))[i] = o;
}

extern "C" void kernel_launch(void* const* d_in, const int* in_sizes, int n_in,
                              void* d_out, int out_size, void* d_ws, size_t ws_size,
                              hipStream_t stream) {
    const float* x      = (const float*)d_in[0];
    const float* gw     = (const float*)d_in[1];
    const float* w_up   = (const float*)d_in[2];
    const float* w_gate = (const float*)d_in[3];
    const float* w_down = (const float*)d_in[4];
    float* out = (float*)d_out;

    char* ws = (char*)d_ws;
    size_t o = 0;
    unsigned short* wTu = (unsigned short*)(ws + o); o += (size_t)NEXP * F_DIM * H_DIM * 2;
    unsigned short* wTg = (unsigned short*)(ws + o); o += (size_t)NEXP * F_DIM * H_DIM * 2;
    unsigned short* wTd = (unsigned short*)(ws + o); o += (size_t)NEXP * H_DIM * F_DIM * 2;
    unsigned short* Xg  = (unsigned short*)(ws + o); o += (size_t)TOTROWS * H_DIM * 2;
    unsigned short* inner = (unsigned short*)(ws + o); o += (size_t)TOTROWS * F_DIM * 2;
    o += 2 * 1024 * 1024;  // pad: tail-row overreads stay in ws
    float* rowWgt = (float*)(ws + o); o += TOTROWS * 4;
    int*   tokRow = (int*)(ws + o);   o += T_TOK * 2 * 4;
    int*   sel    = (int*)(ws + o);   o += T_TOK * 2 * 4;
    float* selw   = (float*)(ws + o); o += T_TOK * 2 * 4;
    int*   cnt    = (int*)(ws + o);   o += 8 * 4;
    int*   fill   = (int*)(ws + o);   o += 8 * 4;
    int*   off_   = (int*)(ws + o);   o += 8 * 4;
    int*   tileExp = (int*)(ws + o);  o += MAXTILES * 4;
    int*   tileM0  = (int*)(ws + o);  o += MAXTILES * 4;
    // part[TOTROWS][H] fp32 aliases wTu+wTg (dead after gemm_upgate; stream-serial)
    float* part = (float*)wTu;

    router_kernel<<<T_TOK / 4, 256, 0, stream>>>(x, gw, sel, selw);
    scan_kernel<<<1, 256, 0, stream>>>(sel, cnt, off_, fill, tileExp, tileM0);
    assign_kernel<<<TOTROWS / 256, 256, 0, stream>>>(sel, selw, off_, fill, rowWgt, tokRow);
    copy_kernel<<<T_TOK, 256, 0, stream>>>(tokRow, x, Xg);
    transpose_cvt_kernel<<<dim3(512, NEXP, 3), 256, 0, stream>>>(w_up, w_gate, w_down, wTu, wTg, wTd);
    gemm_upgate_kernel<<<dim3(F_DIM / 128, 72), 256, 0, stream>>>(Xg, wTu, wTg, inner, tileExp, tileM0, off_, cnt);
    gemm_down_kernel<<<dim3(H_DIM / 128, 72), 256, 0, stream>>>(inner, wTd, part, tileExp, tileM0, off_, cnt, rowWgt);
    combine_kernel<<<T_TOK, 256, 0, stream>>>(part, tokRow, out);
}

// Round 9
// 409.103 us; speedup vs baseline: 2.6748x; 2.6748x over previous
//
#include <hip/hip_runtime.h>
#include <hip/hip_bf16.h>

typedef __bf16 bf16x8 __attribute__((ext_vector_type(8)));
typedef float f32x4 __attribute__((ext_vector_type(4)));

#define T_TOK 4096
#define H_DIM 1024
#define F_DIM 2048
#define NEXP 8
#define TOTROWS 8192   // T_TOK * TOP_K, always exact (top-2 distinct experts)
#define MAXTILES 80    // 128-row tiles

__device__ inline unsigned short f2b(float f) {
    unsigned int u = __float_as_uint(f);
    unsigned int r = (u + 0x7fffu + ((u >> 16) & 1u)) >> 16;
    return (unsigned short)r;
}

// ---------------- router: logits -> softmax -> top2 -> renorm (4 tokens/block, no atomics) ----
__global__ __launch_bounds__(256) void router_kernel(const float* __restrict__ x,
                                                     const float* __restrict__ gw,
                                                     int* __restrict__ sel, float* __restrict__ selw) {
    int t = blockIdx.x * 4 + (threadIdx.x >> 6);
    int lane = threadIdx.x & 63;
    float acc[8] = {0.f,0.f,0.f,0.f,0.f,0.f,0.f,0.f};
    const float* xr = x + (size_t)t * H_DIM;
    for (int h = lane; h < H_DIM; h += 64) {
        float xv = xr[h];
        const float4* g = (const float4*)(gw + h * 8);
        float4 g0 = g[0], g1 = g[1];
        acc[0] += xv * g0.x; acc[1] += xv * g0.y; acc[2] += xv * g0.z; acc[3] += xv * g0.w;
        acc[4] += xv * g1.x; acc[5] += xv * g1.y; acc[6] += xv * g1.z; acc[7] += xv * g1.w;
    }
#pragma unroll
    for (int off = 32; off >= 1; off >>= 1)
#pragma unroll
        for (int e = 0; e < 8; ++e)
            acc[e] += __shfl_down(acc[e], off);
    if (lane == 0) {
        float mx = acc[0];
#pragma unroll
        for (int e = 1; e < 8; ++e) mx = fmaxf(mx, acc[e]);
        float p[8]; float s = 0.f;
#pragma unroll
        for (int e = 0; e < 8; ++e) { p[e] = expf(acc[e] - mx); s += p[e]; }
        float inv_s = 1.f / s;
#pragma unroll
        for (int e = 0; e < 8; ++e) p[e] *= inv_s;
        int e1 = 0; float p1 = p[0];
#pragma unroll
        for (int e = 1; e < 8; ++e) if (p[e] > p1) { p1 = p[e]; e1 = e; }
        int e2 = -1; float p2 = -1.f;
#pragma unroll
        for (int e = 0; e < 8; ++e) { if (e == e1) continue; if (p[e] > p2) { p2 = p[e]; e2 = e; } }
        float inv = 1.f / (p1 + p2);
        sel[t * 2 + 0] = e1; sel[t * 2 + 1] = e2;
        selw[t * 2 + 0] = p1 * inv; selw[t * 2 + 1] = p2 * inv;
    }
}

// ---------------- scan: histogram sel -> cnt/off/fill/tile table (1 block) ----------------
__global__ __launch_bounds__(256) void scan_kernel(const int* __restrict__ sel,
                                                   int* __restrict__ cnt, int* __restrict__ off,
                                                   int* __restrict__ fill,
                                                   int* __restrict__ tileExp, int* __restrict__ tileM0) {
    __shared__ int h[NEXP];
    int tid = threadIdx.x;
    if (tid < NEXP) h[tid] = 0;
    __syncthreads();
    for (int i = tid; i < TOTROWS; i += 256) atomicAdd(&h[sel[i]], 1);
    __syncthreads();
    if (tid == 0) {
        int o = 0;
        for (int e = 0; e < NEXP; ++e) { cnt[e] = h[e]; off[e] = o; o += h[e]; fill[e] = 0; }
        int nt = 0;
        for (int e = 0; e < NEXP; ++e)
            for (int m0 = 0; m0 < h[e]; m0 += 128) { tileExp[nt] = e; tileM0[nt] = m0; nt++; }
        for (int i = nt; i < MAXTILES; ++i) { tileExp[i] = -1; tileM0[i] = 0; }
    }
}

// ---------------- assign: ballot-rank slots, 1 atomic/expert/block (256 atomics total) -------
__global__ __launch_bounds__(256) void assign_kernel(const int* __restrict__ sel,
                                                     const float* __restrict__ selw,
                                                     const int* __restrict__ off,
                                                     int* __restrict__ fill,
                                                     float* __restrict__ rowWgt,
                                                     int* __restrict__ tokRow) {
    __shared__ int wcnt[4][NEXP];
    __shared__ int bbase[NEXP];
    int tid = threadIdx.x, lane = tid & 63, w = tid >> 6;
    int i = blockIdx.x * 256 + tid;          // 32 blocks x 256 = 8192 entries
    int e = sel[i];
    unsigned long long below = (1ULL << lane) - 1;
    int myrank = 0;
#pragma unroll
    for (int x = 0; x < NEXP; ++x) {
        unsigned long long m = __ballot(e == x);
        if (lane == 0) wcnt[w][x] = __popcll(m);
        if (e == x) myrank = __popcll(m & below);
    }
    __syncthreads();
    if (tid < NEXP) {
        int tot = wcnt[0][tid] + wcnt[1][tid] + wcnt[2][tid] + wcnt[3][tid];
        bbase[tid] = atomicAdd(&fill[tid], tot);
    }
    __syncthreads();
    int wb = 0;
    for (int w2 = 0; w2 < w; ++w2) wb += wcnt[w2][e];
    int r = off[e] + bbase[e] + wb + myrank;
    tokRow[i] = r;
    rowWgt[r] = selw[i];
}

// ---------------- copy: x row (bf16) to both expert rows (no atomics) ----------------
__global__ __launch_bounds__(256) void copy_kernel(const int* __restrict__ tokRow,
                                                   const float* __restrict__ x,
                                                   unsigned short* __restrict__ Xg) {
    int t = blockIdx.x;
    int tid = threadIdx.x;
    int r1 = tokRow[t * 2 + 0], r2 = tokRow[t * 2 + 1];
    float4 v = ((const float4*)(x + (size_t)t * H_DIM))[tid];
    ushort4 o;
    o.x = f2b(v.x); o.y = f2b(v.y); o.z = f2b(v.z); o.w = f2b(v.w);
    ((ushort4*)(Xg + (size_t)r1 * H_DIM))[tid] = o;
    ((ushort4*)(Xg + (size_t)r2 * H_DIM))[tid] = o;
}

// ---------------- fused transpose+cvt for all 3 weight tensors ----------------
__global__ __launch_bounds__(256) void transpose_cvt_kernel(
        const float* __restrict__ w_up, const float* __restrict__ w_gate,
        const float* __restrict__ w_down,
        unsigned short* __restrict__ wTu, unsigned short* __restrict__ wTg,
        unsigned short* __restrict__ wTd) {
    __shared__ unsigned short lt[64 * 68];
    int z = blockIdx.z;
    int e = blockIdx.y;
    const float* src; unsigned short* dst; int R, C, tr, tc;
    if (z == 0)      { src = w_up;   dst = wTu; R = H_DIM; C = F_DIM; }
    else if (z == 1) { src = w_gate; dst = wTg; R = H_DIM; C = F_DIM; }
    else             { src = w_down; dst = wTd; R = F_DIM; C = H_DIM; }
    if (R == H_DIM) { tc = blockIdx.x & 31; tr = blockIdx.x >> 5; }
    else            { tc = blockIdx.x & 15; tr = blockIdx.x >> 4; }
    const float* s = src + (size_t)e * H_DIM * F_DIM;
    unsigned short* d = dst + (size_t)e * H_DIM * F_DIM;
    int r0 = tr * 64, c0 = tc * 64;
    int tid = threadIdx.x;
    int fc = tid & 15, row = tid >> 4;
#pragma unroll
    for (int i = 0; i < 4; ++i) {
        int r = row + i * 16;
        float4 v = *(const float4*)(s + (size_t)(r0 + r) * C + c0 + fc * 4);
        lt[(fc * 4 + 0) * 68 + r] = f2b(v.x);
        lt[(fc * 4 + 1) * 68 + r] = f2b(v.y);
        lt[(fc * 4 + 2) * 68 + r] = f2b(v.z);
        lt[(fc * 4 + 3) * 68 + r] = f2b(v.w);
    }
    __syncthreads();
    int ch = tid & 7, cc = tid >> 3;
#pragma unroll
    for (int i = 0; i < 2; ++i) {
        int c = cc + i * 32;
        uint2 lo = *(const uint2*)&lt[c * 68 + ch * 8];
        uint2 hi = *(const uint2*)&lt[c * 68 + ch * 8 + 4];
        uint4 o = make_uint4(lo.x, lo.y, hi.x, hi.y);
        *(uint4*)(d + (size_t)(c0 + c) * R + r0 + ch * 8) = o;
    }
}

// =============== up/gate GEMM: 128x128, BK=32, REG-staged (R5-proven, (256,2)) ===============
// Swizzle v2: slot = chunk ^ ((row>>1)&3).  Fragment-read 16-lane group now sweeps all 8
// 16B bank-groups uniformly (was 4 -> 4-way conflict in R5's chunk^(row&3)).
// Note swz(row) == swz(row+64), so both staged chunks share the formula.
__global__ __launch_bounds__(256, 2) void gemm_upgate_kernel(
        const unsigned short* __restrict__ Xg,
        const unsigned short* __restrict__ wTu,   // [E][F][H] (k-major)
        const unsigned short* __restrict__ wTg,
        unsigned short* __restrict__ inner,       // [TOTROWS][F]
        const int* __restrict__ tileExp, const int* __restrict__ tileM0,
        const int* __restrict__ off, const int* __restrict__ cnt) {
    __shared__ __align__(16) unsigned short la[2][4096];    // 8KB x2 (128x32)
    __shared__ __align__(16) unsigned short lbu[2][4096];
    __shared__ __align__(16) unsigned short lbg[2][4096];   // 48KB total -> 2 blocks/CU
    int bt = blockIdx.y;
    int e = tileExp[bt];
    if (e < 0) return;
    int m0 = tileM0[bt];
    int r0 = off[e] + m0;
    int valid = cnt[e] - m0;
    int f0 = blockIdx.x * 128;
    const unsigned short* aB  = Xg + (size_t)r0 * H_DIM;
    const unsigned short* buW = wTu + (size_t)e * F_DIM * H_DIM + (size_t)f0 * H_DIM;
    const unsigned short* bgW = wTg + (size_t)e * F_DIM * H_DIM + (size_t)f0 * H_DIM;
    int tid = threadIdx.x;
    int lane = tid & 63, wid = tid >> 6;   // 4 waves
    int wm = wid >> 1, wn = wid & 1;       // 2M x 2N -> 64x64 per wave (dual U+G acc)
    int l16 = lane & 15, quad = lane >> 4;

    // staging map: 512 chunks/tile; thread owns chunks tid and tid+256 (all 3 arrays share it)
    int rA0 = tid >> 2, rA1 = rA0 + 64;
    int s0 = rA0 * H_DIM + (tid & 3) * 8;
    int s1 = rA1 * H_DIM + (tid & 3) * 8;
    int d0 = rA0 * 32 + (((tid & 3) ^ ((rA0 >> 1) & 3)) << 3);
    int d1 = rA1 * 32 + (((tid & 3) ^ ((rA1 >> 1) & 3)) << 3);

    // fragment LDS indices (ushort units)
    int aIdx[4], bIdx[4];
#pragma unroll
    for (int i = 0; i < 4; ++i) {
        int lr = wm * 64 + i * 16 + l16;
        aIdx[i] = lr * 32 + ((quad ^ ((lr >> 1) & 3)) << 3);
    }
#pragma unroll
    for (int j = 0; j < 4; ++j) {
        int lr = wn * 64 + j * 16 + l16;
        bIdx[j] = lr * 32 + ((quad ^ ((lr >> 1) & 3)) << 3);
    }

    f32x4 accU[4][4], accG[4][4];
#pragma unroll
    for (int i = 0; i < 4; ++i)
#pragma unroll
        for (int j = 0; j < 4; ++j) { accU[i][j] = (f32x4)0.f; accG[i][j] = (f32x4)0.f; }

    uint4 va0, va1, vu0, vu1, vg0, vg1;   // staging regs (one tile)

#define UPG_LOAD(K0) do {                                        \
    va0 = *(const uint4*)(aB + s0 + (K0));                       \
    va1 = *(const uint4*)(aB + s1 + (K0));                       \
    vu0 = *(const uint4*)(buW + s0 + (K0));                      \
    vu1 = *(const uint4*)(buW + s1 + (K0));                      \
    vg0 = *(const uint4*)(bgW + s0 + (K0));                      \
    vg1 = *(const uint4*)(bgW + s1 + (K0));                      \
} while (0)
#define UPG_WRITE(NB) do {                                       \
    *(uint4*)&la[NB][d0]  = va0;  *(uint4*)&la[NB][d1]  = va1;   \
    *(uint4*)&lbu[NB][d0] = vu0;  *(uint4*)&lbu[NB][d1] = vu1;   \
    *(uint4*)&lbg[NB][d0] = vg0;  *(uint4*)&lbg[NB][d1] = vg1;   \
} while (0)

    // prologue: tile0 -> LDS buf0; tile1 -> regs
    UPG_LOAD(0);
    UPG_WRITE(0);
    UPG_LOAD(32);
    asm volatile("s_waitcnt lgkmcnt(0)" ::: "memory");
    __builtin_amdgcn_s_barrier();
    __builtin_amdgcn_sched_barrier(0);

    for (int t = 0; t < 32; ++t) {        // K = 1024/32 = 32 tiles
        int cur = t & 1, nxt = cur ^ 1;
        const unsigned short* lac = la[cur];
        const unsigned short* luc = lbu[cur];
        const unsigned short* lgc = lbg[cur];
        bf16x8 af[4], bu[4], bg[4];
#pragma unroll
        for (int i = 0; i < 4; ++i) af[i] = *(const bf16x8*)(lac + aIdx[i]);
#pragma unroll
        for (int j = 0; j < 4; ++j) {
            bu[j] = *(const bf16x8*)(luc + bIdx[j]);
            bg[j] = *(const bf16x8*)(lgc + bIdx[j]);
        }
        if (t < 31) UPG_WRITE(nxt);          // publish tile t+1 (regs -> LDS)
        if (t < 30) UPG_LOAD((t + 2) * 32);  // prefetch tile t+2 (global -> regs)
        __builtin_amdgcn_s_setprio(1);
#pragma unroll
        for (int i = 0; i < 4; ++i)
#pragma unroll
            for (int j = 0; j < 4; ++j) {
                accU[i][j] = __builtin_amdgcn_mfma_f32_16x16x32_bf16(af[i], bu[j], accU[i][j], 0, 0, 0);
                accG[i][j] = __builtin_amdgcn_mfma_f32_16x16x32_bf16(af[i], bg[j], accG[i][j], 0, 0, 0);
            }
        __builtin_amdgcn_s_setprio(0);
        asm volatile("s_waitcnt lgkmcnt(0)" ::: "memory");   // ds_writes drained
        __builtin_amdgcn_s_barrier();
        __builtin_amdgcn_sched_barrier(0);
    }
#undef UPG_LOAD
#undef UPG_WRITE

#pragma unroll
    for (int i = 0; i < 4; ++i) {
#pragma unroll
        for (int rr = 0; rr < 4; ++rr) {
            int ml = wm * 64 + i * 16 + quad * 4 + rr;
            if (ml >= valid) continue;
            size_t base = (size_t)(r0 + ml) * F_DIM + f0;
#pragma unroll
            for (int j = 0; j < 4; ++j) {
                float u = accU[i][j][rr];
                float g = accG[i][j][rr];
                float v = u * __builtin_amdgcn_rcpf(1.f + __expf(-u)) * g;   // silu(up)*gate
                inner[base + wn * 64 + j * 16 + l16] = f2b(v);
            }
        }
    }
}

// =============== down GEMM: 128x128, BK=32, REG-staged, 256 thr / 4 waves, 3 blocks/CU =======
// (single acc set fits the (256,3) VGPR cap; swizzle v2 applied)
__global__ __launch_bounds__(256, 3) void gemm_down_kernel(
        const unsigned short* __restrict__ inner,  // [TOTROWS][F]
        const unsigned short* __restrict__ wTd,    // [E][H][F] (k-major)
        float* __restrict__ part,                  // [TOTROWS][H]
        const int* __restrict__ tileExp, const int* __restrict__ tileM0,
        const int* __restrict__ off, const int* __restrict__ cnt,
        const float* __restrict__ rowWgt) {
    __shared__ __align__(16) unsigned short la[2][4096];   // 8KB x2 (128x32)
    __shared__ __align__(16) unsigned short lb[2][4096];   // 32KB total -> 3 blocks/CU
    int bt = blockIdx.y;
    int e = tileExp[bt];
    if (e < 0) return;
    int m0 = tileM0[bt];
    int r0 = off[e] + m0;
    int valid = cnt[e] - m0;
    int h0 = blockIdx.x * 128;
    const unsigned short* aB = inner + (size_t)r0 * F_DIM;
    const unsigned short* bp = wTd + (size_t)e * H_DIM * F_DIM + (size_t)h0 * F_DIM;
    int tid = threadIdx.x;
    int lane = tid & 63, wid = tid >> 6;   // 4 waves
    int wm = wid >> 1, wn = wid & 1;       // 2M x 2N -> 64x64 per wave
    int l16 = lane & 15, quad = lane >> 4;

    int rA0 = tid >> 2, rA1 = rA0 + 64;
    int s0 = rA0 * F_DIM + (tid & 3) * 8;
    int s1 = rA1 * F_DIM + (tid & 3) * 8;
    int d0 = rA0 * 32 + (((tid & 3) ^ ((rA0 >> 1) & 3)) << 3);
    int d1 = rA1 * 32 + (((tid & 3) ^ ((rA1 >> 1) & 3)) << 3);

    int aIdx[4], bIdx[4];
#pragma unroll
    for (int i = 0; i < 4; ++i) {
        int lr = wm * 64 + i * 16 + l16;
        aIdx[i] = lr * 32 + ((quad ^ ((lr >> 1) & 3)) << 3);
    }
#pragma unroll
    for (int j = 0; j < 4; ++j) {
        int lr = wn * 64 + j * 16 + l16;
        bIdx[j] = lr * 32 + ((quad ^ ((lr >> 1) & 3)) << 3);
    }

    f32x4 acc[4][4];
#pragma unroll
    for (int i = 0; i < 4; ++i)
#pragma unroll
        for (int j = 0; j < 4; ++j) acc[i][j] = (f32x4)0.f;

    uint4 va0, va1, vb0, vb1;

#define DWN_LOAD(K0) do {                                        \
    va0 = *(const uint4*)(aB + s0 + (K0));                       \
    va1 = *(const uint4*)(aB + s1 + (K0));                       \
    vb0 = *(const uint4*)(bp + s0 + (K0));                       \
    vb1 = *(const uint4*)(bp + s1 + (K0));                       \
} while (0)
#define DWN_WRITE(NB) do {                                       \
    *(uint4*)&la[NB][d0] = va0;  *(uint4*)&la[NB][d1] = va1;     \
    *(uint4*)&lb[NB][d0] = vb0;  *(uint4*)&lb[NB][d1] = vb1;     \
} while (0)

    DWN_LOAD(0);
    DWN_WRITE(0);
    DWN_LOAD(32);
    asm volatile("s_waitcnt lgkmcnt(0)" ::: "memory");
    __builtin_amdgcn_s_barrier();
    __builtin_amdgcn_sched_barrier(0);

    for (int t = 0; t < 64; ++t) {        // K = 2048/32 = 64 tiles
        int cur = t & 1, nxt = cur ^ 1;
        const unsigned short* lac = la[cur];
        const unsigned short* lbc = lb[cur];
        bf16x8 af[4], bw[4];
#pragma unroll
        for (int i = 0; i < 4; ++i) af[i] = *(const bf16x8*)(lac + aIdx[i]);
#pragma unroll
        for (int j = 0; j < 4; ++j) bw[j] = *(const bf16x8*)(lbc + bIdx[j]);
        if (t < 63) DWN_WRITE(nxt);
        if (t < 62) DWN_LOAD((t + 2) * 32);
        __builtin_amdgcn_s_setprio(1);
#pragma unroll
        for (int i = 0; i < 4; ++i)
#pragma unroll
            for (int j = 0; j < 4; ++j)
                acc[i][j] = __builtin_amdgcn_mfma_f32_16x16x32_bf16(af[i], bw[j], acc[i][j], 0, 0, 0);
        __builtin_amdgcn_s_setprio(0);
        asm volatile("s_waitcnt lgkmcnt(0)" ::: "memory");
        __builtin_amdgcn_s_barrier();
        __builtin_amdgcn_sched_barrier(0);
    }
#undef DWN_LOAD
#undef DWN_WRITE

#pragma unroll
    for (int i = 0; i < 4; ++i) {
#pragma unroll
        for (int rr = 0; rr < 4; ++rr) {
            int ml = wm * 64 + i * 16 + quad * 4 + rr;
            if (ml >= valid) continue;
            int gr = r0 + ml;
            float w = rowWgt[gr];
            float* orow = part + (size_t)gr * H_DIM + h0;
#pragma unroll
            for (int j = 0; j < 4; ++j)
                orow[wn * 64 + j * 16 + l16] = w * acc[i][j][rr];
        }
    }
}

// ---------------- combine: out[t] = part[r1] + part[r2] ----------------
__global__ __launch_bounds__(256) void combine_kernel(const float* __restrict__ part,
                                                      const int* __restrict__ tokRow,
                                                      float* __restrict__ out) {
    int t = blockIdx.x;
    int r1 = tokRow[t * 2 + 0], r2 = tokRow[t * 2 + 1];
    int i = threadIdx.x;
    float4 a = ((const float4*)(part + (size_t)r1 * H_DIM))[i];
    float4 b = ((const float4*)(part + (size_t)r2 * H_DIM))[i];
    float4 o;
    o.x = a.x + b.x; o.y = a.y + b.y; o.z = a.z + b.z; o.w = a.w + b.w;
    ((float4*)(out + (size_t)t * H_DIM))[i] = o;
}

extern "C" void kernel_launch(void* const* d_in, const int* in_sizes, int n_in,
                              void* d_out, int out_size, void* d_ws, size_t ws_size,
                              hipStream_t stream) {
    const float* x      = (const float*)d_in[0];
    const float* gw     = (const float*)d_in[1];
    const float* w_up   = (const float*)d_in[2];
    const float* w_gate = (const float*)d_in[3];
    const float* w_down = (const float*)d_in[4];
    float* out = (float*)d_out;

    char* ws = (char*)d_ws;
    size_t o = 0;
    unsigned short* wTu = (unsigned short*)(ws + o); o += (size_t)NEXP * F_DIM * H_DIM * 2;
    unsigned short* wTg = (unsigned short*)(ws + o); o += (size_t)NEXP * F_DIM * H_DIM * 2;
    unsigned short* wTd = (unsigned short*)(ws + o); o += (size_t)NEXP * H_DIM * F_DIM * 2;
    unsigned short* Xg  = (unsigned short*)(ws + o); o += (size_t)TOTROWS * H_DIM * 2;
    unsigned short* inner = (unsigned short*)(ws + o); o += (size_t)TOTROWS * F_DIM * 2;
    o += 2 * 1024 * 1024;  // pad: tail-row overreads stay in ws
    float* rowWgt = (float*)(ws + o); o += TOTROWS * 4;
    int*   tokRow = (int*)(ws + o);   o += T_TOK * 2 * 4;
    int*   sel    = (int*)(ws + o);   o += T_TOK * 2 * 4;
    float* selw   = (float*)(ws + o); o += T_TOK * 2 * 4;
    int*   cnt    = (int*)(ws + o);   o += 8 * 4;
    int*   fill   = (int*)(ws + o);   o += 8 * 4;
    int*   off_   = (int*)(ws + o);   o += 8 * 4;
    int*   tileExp = (int*)(ws + o);  o += MAXTILES * 4;
    int*   tileM0  = (int*)(ws + o);  o += MAXTILES * 4;
    // part[TOTROWS][H] fp32 aliases wTu+wTg (dead after gemm_upgate; stream-serial)
    float* part = (float*)wTu;

    router_kernel<<<T_TOK / 4, 256, 0, stream>>>(x, gw, sel, selw);
    scan_kernel<<<1, 256, 0, stream>>>(sel, cnt, off_, fill, tileExp, tileM0);
    assign_kernel<<<TOTROWS / 256, 256, 0, stream>>>(sel, selw, off_, fill, rowWgt, tokRow);
    copy_kernel<<<T_TOK, 256, 0, stream>>>(tokRow, x, Xg);
    transpose_cvt_kernel<<<dim3(512, NEXP, 3), 256, 0, stream>>>(w_up, w_gate, w_down, wTu, wTg, wTd);
    gemm_upgate_kernel<<<dim3(F_DIM / 128, 72), 256, 0, stream>>>(Xg, wTu, wTg, inner, tileExp, tileM0, off_, cnt);
    gemm_down_kernel<<<dim3(H_DIM / 128, 72), 256, 0, stream>>>(inner, wTd, part, tileExp, tileM0, off_, cnt, rowWgt);
    combine_kernel<<<T_TOK, 256, 0, stream>>>(part, tokRow, out);
}